// Round 15
// baseline (344.555 us; speedup 1.0000x reference)
//
#include <hip/hip_runtime.h>
#include <math.h>

#define B_ 2
#define H_ 16
#define S_ 2048
#define CTX_ 1024
#define VD_ 288
#define VD2_ 576
#define FFN_ 512
#define FFNH_ 256
#define NH1_ 17
#define EPSILON_ 0.066f
#define LN_EPS_ 1e-5f
#define TPB_ 8                    // tokens per block
#define NBLK_ (B_ * S_ / TPB_)    // 512 blocks -> 2 blocks/CU
#define NTHR_ 576                 // 8 MLP waves + 1 prefetch wave

typedef float vfloat4 __attribute__((ext_vector_type(4)));

__device__ __forceinline__ float gelu_exact(float x) {
    return 0.5f * x * (1.0f + erff(x * 0.70710678118654752440f));
}
__device__ __forceinline__ vfloat4 gelu4(vfloat4 v) {
    vfloat4 o;
    o.x = gelu_exact(v.x); o.y = gelu_exact(v.y);
    o.z = gelu_exact(v.z); o.w = gelu_exact(v.w);
    return o;
}

// one-block fused histogram (proven round 4)
__global__ __launch_bounds__(1024) void count_kernel(
    const int* __restrict__ ids, int* __restrict__ counts)
{
    __shared__ int hist[CTX_];
    const int t = threadIdx.x;          // 1024 threads == CTX_
    hist[t] = 0;
    __syncthreads();
    #pragma unroll
    for (int r = 0; r < (B_ * S_) / 1024; ++r)
        atomicAdd(&hist[ids[t + 1024 * r]], 1);
    __syncthreads();
    counts[t] = hist[t];
}

// Round-10 kernel (proven 249.2) + a 9th wave per block dedicated to
// prefetching the block's first-half scores region into L2/LLC DURING the
// MLP phases (HBM is otherwise idle for ~75 us). 268 MB aggregate ~= LLC
// size; scale loop later reads that half as cache hits. Waves 0-7 run the
// proven MLP verbatim.
__global__ __launch_bounds__(NTHR_, 4) void token_mlp_scale_kernel(
    const int* __restrict__ ids, const int* __restrict__ counts,
    const float* __restrict__ embW,
    const float* __restrict__ lnvw, const float* __restrict__ lnvb,
    const float* __restrict__ pW1, const float* __restrict__ pb1,
    const float* __restrict__ pW2, const float* __restrict__ pb2,
    const float* __restrict__ lncw, const float* __restrict__ lncb,
    const float* __restrict__ fW1, const float* __restrict__ fb1,
    const float* __restrict__ fW2, const float* __restrict__ fb2,
    const float* __restrict__ fW3, const float* __restrict__ fb3,
    const vfloat4* __restrict__ scores, vfloat4* __restrict__ out)
{
    // activations transposed: [dim][token]; 8-token row = 32 B
    __shared__ __align__(16) float va[VD_][TPB_];      //  9.2 KB
    __shared__ __align__(16) float ha[VD2_][TPB_];     // 18.4 KB
    __shared__ __align__(16) float comb17[NH1_][TPB_]; //  0.5 KB
    __shared__ __align__(16) float h2a[FFN_][TPB_];    // 16.4 KB
    __shared__ __align__(16) float h3a[FFNH_][TPB_];   //  8.2 KB
    __shared__ float wl[TPB_];
    // total 52.8 KB -> 2 blocks/CU (18 waves/CU)

    const int tid  = threadIdx.x;
    const int tok0 = blockIdx.x * TPB_;
    const int wid  = tid >> 6;     // wave 0..8
    const int cthr = tid & 63;
    const int quad = wid & 1;      // token quad (MLP waves)
    const int cq   = wid >> 1;     // column quarter (MLP waves)
    const int tq   = quad * 4;

    // ---- wave-8 prefetch state ----
    // Block's stream read region in m-order: m -> idx identical to the scale
    // loop below. Prefetch instrs cover vf4 indices [pm*64, (pm+n)*64).
    float pacc = 0.f;
    int   pm   = 0;
    const int g0 = blockIdx.x * TPB_;
    auto prefetch = [&](int n) {
        for (int i = 0; i < n; i += 8) {
            vfloat4 x[8];
            #pragma unroll
            for (int u = 0; u < 8; ++u) {
                int m   = (pm + i + u) * 64 + cthr;
                int rr  = m >> 9;
                int off = m & 511;
                int j   = rr & 7;
                int h   = rr >> 3;
                int gt  = g0 + j;
                long row = (long)(gt >> 11) * (H_ * S_) + h * S_ + (gt & (S_ - 1));
                x[u] = scores[row * (S_ / 4) + off];
            }
            #pragma unroll
            for (int u = 0; u < 8; ++u) pacc += x[u].x;
        }
        pm += n;
    };

    // ---- phase 0: embedding gather + LayerNorm(288); one wave per token ----
    if (wid == 8) {
        prefetch(32);
    } else {
        const int w  = wid;          // token 0..7
        const int l  = cthr;
        const int id = ids[tok0 + w];
        float x[5];
        float s = 0.f, sq = 0.f;
        #pragma unroll
        for (int r = 0; r < 4; ++r) {
            float xv = embW[id * VD_ + l + 64 * r];
            x[r] = xv; s += xv; sq += xv * xv;
        }
        x[4] = 0.f;
        if (l < 32) {
            float xv = embW[id * VD_ + 256 + l];
            x[4] = xv; s += xv; sq += xv * xv;
        }
        #pragma unroll
        for (int m = 32; m >= 1; m >>= 1) {
            s  += __shfl_xor(s,  m, 64);
            sq += __shfl_xor(sq, m, 64);
        }
        float mu   = s * (1.f / VD_);
        float var  = sq * (1.f / VD_) - mu * mu;
        float rstd = rsqrtf(var + LN_EPS_);
        #pragma unroll
        for (int r = 0; r < 4; ++r) {
            int i = l + 64 * r;
            va[i][w] = (x[r] - mu) * rstd * lnvw[i] + lnvb[i];
        }
        if (l < 32) {
            int i = 256 + l;
            va[i][w] = (x[4] - mu) * rstd * lnvw[i] + lnvb[i];
        }
    }
    __syncthreads();

    // ---- phase 1: ha = gelu(va @ pW1 + pb1) [288 -> 576] ----
    if (wid == 8) {
        prefetch(160);
    } else {
        vfloat4 a0 = 0, a1 = 0, a2 = 0;
        const int cb = 144 * cq;
        const bool extra = (cthr < 16);        // cols cb+128..cb+143
        for (int k = 0; k < VD_; k += 8) {     // 36 groups
            float w0[8], w1[8], w2[8];
            #pragma unroll
            for (int u = 0; u < 8; ++u) {
                const float* wr = &pW1[(k + u) * VD2_ + cb + cthr];
                w0[u] = wr[0]; w1[u] = wr[64];
                if (extra) w2[u] = wr[128];
            }
            vfloat4 v[8];
            #pragma unroll
            for (int u = 0; u < 8; ++u) v[u] = *(const vfloat4*)&va[k + u][tq];
            #pragma unroll
            for (int u = 0; u < 8; ++u) {
                a0 += w0[u] * v[u];
                a1 += w1[u] * v[u];
                if (extra) a2 += w2[u] * v[u];
            }
        }
        int col = cb + cthr;
        *(vfloat4*)&ha[col     ][tq] = gelu4(a0 + pb1[col]);
        *(vfloat4*)&ha[col + 64][tq] = gelu4(a1 + pb1[col + 64]);
        if (extra)
            *(vfloat4*)&ha[col + 128][tq] = gelu4(a2 + pb1[col + 128]);
    }
    __syncthreads();

    // ---- phase 2: valence = tanh(ha @ pW2 + pb2) [576 -> 16] + occ ----
    if (wid == 8) {
        prefetch(96);
    } else if (wid < 4) {
        const int t0  = wid * 2;
        const int col = cthr & 15;
        const int ks  = cthr >> 4;      // 4-way K split (144 each)
        float2 acc = make_float2(0.f, 0.f);
        for (int k = ks * 144; k < ks * 144 + 144; k += 8) {
            float w[8]; float2 v[8];
            #pragma unroll
            for (int u = 0; u < 8; ++u) w[u] = pW2[(k + u) * H_ + col];
            #pragma unroll
            for (int u = 0; u < 8; ++u) v[u] = *(const float2*)&ha[k + u][t0];
            #pragma unroll
            for (int u = 0; u < 8; ++u) {
                acc.x += w[u] * v[u].x; acc.y += w[u] * v[u].y;
            }
        }
        acc.x += __shfl_xor(acc.x, 16, 64); acc.y += __shfl_xor(acc.y, 16, 64);
        acc.x += __shfl_xor(acc.x, 32, 64); acc.y += __shfl_xor(acc.y, 32, 64);
        if (cthr < 16) {
            float b = pb2[col];
            float2 o = make_float2(tanhf(acc.x + b), tanhf(acc.y + b));
            *(float2*)&comb17[1 + col][t0] = o;
        }
        if (cthr == 16) {
            #pragma unroll
            for (int j = 0; j < 2; ++j) {
                int t = t0 + j;
                int id = ids[tok0 + t];
                float c = (float)counts[id];
                if (c < 1.f) c = 1.f;
                comb17[0][t] = log1pf(c);
            }
        }
    }
    __syncthreads();

    // ---- phase 3: LayerNorm(17), one thread per token ----
    if (wid == 8) prefetch(16);
    if (tid < TPB_) {
        float vals[NH1_];
        float s = 0.f;
        #pragma unroll
        for (int i = 0; i < NH1_; ++i) { vals[i] = comb17[i][tid]; s += vals[i]; }
        float mu = s / NH1_;
        float vq = 0.f;
        #pragma unroll
        for (int i = 0; i < NH1_; ++i) { float d = vals[i] - mu; vq += d * d; }
        float r = rsqrtf(vq / NH1_ + LN_EPS_);
        #pragma unroll
        for (int i = 0; i < NH1_; ++i)
            comb17[i][tid] = (vals[i] - mu) * r * lncw[i] + lncb[i];
    }
    __syncthreads();

    // ---- phase 4: h2 = gelu(comb @ fW1 + fb1) [17 -> 512] ----
    if (wid == 8) {
        prefetch(48);
    } else {
        vfloat4 a0 = 0, a1 = 0;
        const int cb = 128 * cq;
        #pragma unroll
        for (int k = 0; k < NH1_; ++k) {
            vfloat4 v = *(const vfloat4*)&comb17[k][tq];
            const float* wr = &fW1[k * FFN_ + cb + cthr];
            a0 += wr[0] * v;
            a1 += wr[64] * v;
        }
        int col = cb + cthr;
        *(vfloat4*)&h2a[col     ][tq] = gelu4(a0 + fb1[col]);
        *(vfloat4*)&h2a[col + 64][tq] = gelu4(a1 + fb1[col + 64]);
    }
    __syncthreads();

    // ---- phase 5: h3 = gelu(h2 @ fW2 + fb2) [512 -> 256] ----
    if (wid == 8) {
        prefetch(160);   // total 512 instrs = 512 KB = block's read half
    } else {
        vfloat4 a0 = 0;
        const int cb = 64 * cq;
        for (int k = 0; k < FFN_; k += 8) {    // 64 groups
            float w0[8]; vfloat4 v[8];
            #pragma unroll
            for (int u = 0; u < 8; ++u)
                w0[u] = fW2[(k + u) * FFNH_ + cb + cthr];
            #pragma unroll
            for (int u = 0; u < 8; ++u) v[u] = *(const vfloat4*)&h2a[k + u][tq];
            #pragma unroll
            for (int u = 0; u < 8; ++u) a0 += w0[u] * v[u];
        }
        int col = cb + cthr;
        *(vfloat4*)&h3a[col][tq] = gelu4(a0 + fb2[col]);
    }
    __syncthreads();

    // ---- phase 6: mod = tanh(h3 . fW3 + fb3); one wave per token ----
    if (wid < 8) {
        const int tt = wid;
        const int l  = cthr;
        float acc = 0.f;
        #pragma unroll
        for (int r = 0; r < FFNH_ / 64; ++r) {
            int k = l + 64 * r;
            acc += h3a[k][tt] * fW3[k];
        }
        #pragma unroll
        for (int m = 32; m >= 1; m >>= 1) acc += __shfl_xor(acc, m, 64);
        if (l == 0)
            wl[tt] = 1.0f + EPSILON_ * tanhf(acc + fb3[0]);
    }
    __syncthreads();

    // keep the prefetch accumulator live (prevents DCE of prefetch loads)
    asm volatile("" :: "v"(pacc));

    // ---- fused scale: this block's 8 tokens x 16 heads x 2048 floats ----
    // first half (m < 32768) was prefetched -> regular load (LLC hit);
    // cold half -> nontemporal load. NT stores throughout.
    {
        #pragma unroll 4
        for (int m = tid; m < TPB_ * H_ * (S_ / 4); m += NTHR_) {
            int rr  = m >> 9;             // local row 0..127
            int off = m & 511;
            int j   = rr & 7;             // token within block
            int h   = rr >> 3;            // head
            int g   = g0 + j;
            long row = (long)(g >> 11) * (H_ * S_) + h * S_ + (g & (S_ - 1));
            long idx = row * (S_ / 4) + off;
            vfloat4 x = (m < 32768) ? scores[idx]
                                    : __builtin_nontemporal_load(&scores[idx]);
            x *= wl[j];
            __builtin_nontemporal_store(x, &out[idx]);
        }
    }
}

extern "C" void kernel_launch(void* const* d_in, const int* in_sizes, int n_in,
                              void* d_out, int out_size, void* d_ws, size_t ws_size,
                              hipStream_t stream) {
    const float* scores = (const float*)d_in[0];
    const int*   ids    = (const int*)  d_in[1];
    const float* embW   = (const float*)d_in[2];
    const float* lnvw   = (const float*)d_in[3];
    const float* lnvb   = (const float*)d_in[4];
    const float* pW1    = (const float*)d_in[5];
    const float* pb1    = (const float*)d_in[6];
    const float* pW2    = (const float*)d_in[7];
    const float* pb2    = (const float*)d_in[8];
    const float* lncw   = (const float*)d_in[9];
    const float* lncb   = (const float*)d_in[10];
    const float* fW1    = (const float*)d_in[11];
    const float* fb1    = (const float*)d_in[12];
    const float* fW2    = (const float*)d_in[13];
    const float* fb2    = (const float*)d_in[14];
    const float* fW3    = (const float*)d_in[15];
    const float* fb3    = (const float*)d_in[16];

    int* counts = (int*)d_ws;

    count_kernel<<<1, 1024, 0, stream>>>(ids, counts);
    token_mlp_scale_kernel<<<NBLK_, NTHR_, 0, stream>>>(
        ids, counts, embW, lnvw, lnvb, pW1, pb1, pW2, pb2,
        lncw, lncb, fW1, fb1, fW2, fb2, fW3, fb3,
        (const vfloat4*)scores, (vfloat4*)d_out);
}

// Round 16
// 245.242 us; speedup vs baseline: 1.4050x; 1.4050x over previous
//
#include <hip/hip_runtime.h>
#include <math.h>

#define B_ 2
#define H_ 16
#define S_ 2048
#define CTX_ 1024
#define VD_ 288
#define VD2_ 576
#define FFN_ 512
#define FFNH_ 256
#define NH1_ 17
#define EPSILON_ 0.066f
#define LN_EPS_ 1e-5f
#define TPB_ 8                    // tokens per block
#define NBLK_ (B_ * S_ / TPB_)    // 512 blocks -> 2 blocks/CU

typedef float vfloat4 __attribute__((ext_vector_type(4)));

__device__ __forceinline__ float gelu_exact(float x) {
    return 0.5f * x * (1.0f + erff(x * 0.70710678118654752440f));
}
__device__ __forceinline__ vfloat4 gelu4(vfloat4 v) {
    vfloat4 o;
    o.x = gelu_exact(v.x); o.y = gelu_exact(v.y);
    o.z = gelu_exact(v.z); o.w = gelu_exact(v.w);
    return o;
}

// one-block fused histogram (proven round 4)
__global__ __launch_bounds__(1024) void count_kernel(
    const int* __restrict__ ids, int* __restrict__ counts)
{
    __shared__ int hist[CTX_];
    const int t = threadIdx.x;          // 1024 threads == CTX_
    hist[t] = 0;
    __syncthreads();
    #pragma unroll
    for (int r = 0; r < (B_ * S_) / 1024; ++r)
        atomicAdd(&hist[ids[t + 1024 * r]], 1);
    __syncthreads();
    counts[t] = hist[t];
}

// EXACT round-10 kernel (session optimum, verified 249.2 / 251.4 us).
// TPB=8, 512 thr = 8 waves = 2 token-quads x 4 column-quarters, grouped
// register prefetch in P1/P2/P5, 52.8 KB LDS -> 2 blocks/CU = 4 waves/SIMD,
// scale stream fused at the tail with wl in LDS, NT load/store streaming.
// Structural budget: stream 171 us (measured HBM ceiling) + MLP ~75 us
// (latency-bound serial chain) + ~5 us fixed.
__global__ __launch_bounds__(512, 4) void token_mlp_scale_kernel(
    const int* __restrict__ ids, const int* __restrict__ counts,
    const float* __restrict__ embW,
    const float* __restrict__ lnvw, const float* __restrict__ lnvb,
    const float* __restrict__ pW1, const float* __restrict__ pb1,
    const float* __restrict__ pW2, const float* __restrict__ pb2,
    const float* __restrict__ lncw, const float* __restrict__ lncb,
    const float* __restrict__ fW1, const float* __restrict__ fb1,
    const float* __restrict__ fW2, const float* __restrict__ fb2,
    const float* __restrict__ fW3, const float* __restrict__ fb3,
    const vfloat4* __restrict__ scores, vfloat4* __restrict__ out)
{
    // activations transposed: [dim][token]; 8-token row = 32 B
    __shared__ __align__(16) float va[VD_][TPB_];      //  9.2 KB
    __shared__ __align__(16) float ha[VD2_][TPB_];     // 18.4 KB
    __shared__ __align__(16) float comb17[NH1_][TPB_]; //  0.5 KB
    __shared__ __align__(16) float h2a[FFN_][TPB_];    // 16.4 KB
    __shared__ __align__(16) float h3a[FFNH_][TPB_];   //  8.2 KB
    __shared__ float wl[TPB_];
    // total 52.8 KB -> 2 blocks/CU

    const int tid  = threadIdx.x;
    const int tok0 = blockIdx.x * TPB_;
    const int wid  = tid >> 6;     // wave 0..7
    const int cthr = tid & 63;
    const int quad = wid & 1;      // token quad 0/1 (tokens 4q..4q+3)
    const int cq   = wid >> 1;     // column quarter 0..3
    const int tq   = quad * 4;

    // ---- phase 0: embedding gather + LayerNorm(288); one wave per token ----
    {
        const int w  = wid;          // token 0..7
        const int l  = cthr;
        const int id = ids[tok0 + w];
        float x[5];
        float s = 0.f, sq = 0.f;
        #pragma unroll
        for (int r = 0; r < 4; ++r) {
            float xv = embW[id * VD_ + l + 64 * r];
            x[r] = xv; s += xv; sq += xv * xv;
        }
        x[4] = 0.f;
        if (l < 32) {
            float xv = embW[id * VD_ + 256 + l];
            x[4] = xv; s += xv; sq += xv * xv;
        }
        #pragma unroll
        for (int m = 32; m >= 1; m >>= 1) {
            s  += __shfl_xor(s,  m, 64);
            sq += __shfl_xor(sq, m, 64);
        }
        float mu   = s * (1.f / VD_);
        float var  = sq * (1.f / VD_) - mu * mu;
        float rstd = rsqrtf(var + LN_EPS_);
        #pragma unroll
        for (int r = 0; r < 4; ++r) {
            int i = l + 64 * r;
            va[i][w] = (x[r] - mu) * rstd * lnvw[i] + lnvb[i];
        }
        if (l < 32) {
            int i = 256 + l;
            va[i][w] = (x[4] - mu) * rstd * lnvw[i] + lnvb[i];
        }
    }
    __syncthreads();

    // ---- phase 1: ha = gelu(va @ pW1 + pb1) [288 -> 576] ----
    // wave = 4 tokens x 144 cols (quarter); k grouped x8, fan 2.25
    {
        vfloat4 a0 = 0, a1 = 0, a2 = 0;
        const int cb = 144 * cq;
        const bool extra = (cthr < 16);        // cols cb+128..cb+143
        for (int k = 0; k < VD_; k += 8) {     // 36 groups
            float w0[8], w1[8], w2[8];
            #pragma unroll
            for (int u = 0; u < 8; ++u) {
                const float* wr = &pW1[(k + u) * VD2_ + cb + cthr];
                w0[u] = wr[0]; w1[u] = wr[64];
                if (extra) w2[u] = wr[128];
            }
            vfloat4 v[8];
            #pragma unroll
            for (int u = 0; u < 8; ++u) v[u] = *(const vfloat4*)&va[k + u][tq];
            #pragma unroll
            for (int u = 0; u < 8; ++u) {
                a0 += w0[u] * v[u];
                a1 += w1[u] * v[u];
                if (extra) a2 += w2[u] * v[u];
            }
        }
        int col = cb + cthr;
        *(vfloat4*)&ha[col     ][tq] = gelu4(a0 + pb1[col]);
        *(vfloat4*)&ha[col + 64][tq] = gelu4(a1 + pb1[col + 64]);
        if (extra)
            *(vfloat4*)&ha[col + 128][tq] = gelu4(a2 + pb1[col + 128]);
    }
    __syncthreads();

    // ---- phase 2: valence = tanh(ha @ pW2 + pb2) [576 -> 16] + occ ----
    // waves 0..3 only; k grouped x8
    if (wid < 4) {
        const int t0  = wid * 2;
        const int col = cthr & 15;
        const int ks  = cthr >> 4;      // 4-way K split (144 each)
        float2 acc = make_float2(0.f, 0.f);
        for (int k = ks * 144; k < ks * 144 + 144; k += 8) {
            float w[8]; float2 v[8];
            #pragma unroll
            for (int u = 0; u < 8; ++u) w[u] = pW2[(k + u) * H_ + col];
            #pragma unroll
            for (int u = 0; u < 8; ++u) v[u] = *(const float2*)&ha[k + u][t0];
            #pragma unroll
            for (int u = 0; u < 8; ++u) {
                acc.x += w[u] * v[u].x; acc.y += w[u] * v[u].y;
            }
        }
        acc.x += __shfl_xor(acc.x, 16, 64); acc.y += __shfl_xor(acc.y, 16, 64);
        acc.x += __shfl_xor(acc.x, 32, 64); acc.y += __shfl_xor(acc.y, 32, 64);
        if (cthr < 16) {
            float b = pb2[col];
            float2 o = make_float2(tanhf(acc.x + b), tanhf(acc.y + b));
            *(float2*)&comb17[1 + col][t0] = o;
        }
        if (cthr == 16) {
            #pragma unroll
            for (int j = 0; j < 2; ++j) {
                int t = t0 + j;
                int id = ids[tok0 + t];
                float c = (float)counts[id];
                if (c < 1.f) c = 1.f;
                comb17[0][t] = log1pf(c);
            }
        }
    }
    __syncthreads();

    // ---- phase 3: LayerNorm(17), one thread per token ----
    if (tid < TPB_) {
        float vals[NH1_];
        float s = 0.f;
        #pragma unroll
        for (int i = 0; i < NH1_; ++i) { vals[i] = comb17[i][tid]; s += vals[i]; }
        float mu = s / NH1_;
        float vq = 0.f;
        #pragma unroll
        for (int i = 0; i < NH1_; ++i) { float d = vals[i] - mu; vq += d * d; }
        float r = rsqrtf(vq / NH1_ + LN_EPS_);
        #pragma unroll
        for (int i = 0; i < NH1_; ++i)
            comb17[i][tid] = (vals[i] - mu) * r * lncw[i] + lncb[i];
    }
    __syncthreads();

    // ---- phase 4: h2 = gelu(comb @ fW1 + fb1) [17 -> 512] ----
    // wave = 4 tokens x 128 cols (quarter); 17 k fully unrolled, fan-2
    {
        vfloat4 a0 = 0, a1 = 0;
        const int cb = 128 * cq;
        #pragma unroll
        for (int k = 0; k < NH1_; ++k) {
            vfloat4 v = *(const vfloat4*)&comb17[k][tq];
            const float* wr = &fW1[k * FFN_ + cb + cthr];
            a0 += wr[0] * v;
            a1 += wr[64] * v;
        }
        int col = cb + cthr;
        *(vfloat4*)&h2a[col     ][tq] = gelu4(a0 + fb1[col]);
        *(vfloat4*)&h2a[col + 64][tq] = gelu4(a1 + fb1[col + 64]);
    }
    __syncthreads();

    // ---- phase 5: h3 = gelu(h2 @ fW2 + fb2) [512 -> 256] ----
    // wave = 4 tokens x 64 cols (quarter); fan-1, k grouped x8
    {
        vfloat4 a0 = 0;
        const int cb = 64 * cq;
        for (int k = 0; k < FFN_; k += 8) {    // 64 groups
            float w0[8]; vfloat4 v[8];
            #pragma unroll
            for (int u = 0; u < 8; ++u)
                w0[u] = fW2[(k + u) * FFNH_ + cb + cthr];
            #pragma unroll
            for (int u = 0; u < 8; ++u) v[u] = *(const vfloat4*)&h2a[k + u][tq];
            #pragma unroll
            for (int u = 0; u < 8; ++u) a0 += w0[u] * v[u];
        }
        int col = cb + cthr;
        *(vfloat4*)&h3a[col][tq] = gelu4(a0 + fb2[col]);
    }
    __syncthreads();

    // ---- phase 6: mod = tanh(h3 . fW3 + fb3); one wave per token ----
    {
        const int tt = wid;
        const int l  = cthr;
        float acc = 0.f;
        #pragma unroll
        for (int r = 0; r < FFNH_ / 64; ++r) {
            int k = l + 64 * r;
            acc += h3a[k][tt] * fW3[k];
        }
        #pragma unroll
        for (int m = 32; m >= 1; m >>= 1) acc += __shfl_xor(acc, m, 64);
        if (l == 0)
            wl[tt] = 1.0f + EPSILON_ * tanhf(acc + fb3[0]);
    }
    __syncthreads();

    // ---- fused scale: this block's 8 tokens x 16 heads x 2048 floats ----
    {
        const int g0 = blockIdx.x * TPB_;
        #pragma unroll 4
        for (int m = tid; m < TPB_ * H_ * (S_ / 4); m += 512) {
            int rr  = m >> 9;             // local row 0..127
            int off = m & 511;
            int j   = rr & 7;             // token within block
            int h   = rr >> 3;            // head
            int g   = g0 + j;
            long row = (long)(g >> 11) * (H_ * S_) + h * S_ + (g & (S_ - 1));
            long idx = row * (S_ / 4) + off;
            vfloat4 x = __builtin_nontemporal_load(&scores[idx]);
            x *= wl[j];
            __builtin_nontemporal_store(x, &out[idx]);
        }
    }
}

extern "C" void kernel_launch(void* const* d_in, const int* in_sizes, int n_in,
                              void* d_out, int out_size, void* d_ws, size_t ws_size,
                              hipStream_t stream) {
    const float* scores = (const float*)d_in[0];
    const int*   ids    = (const int*)  d_in[1];
    const float* embW   = (const float*)d_in[2];
    const float* lnvw   = (const float*)d_in[3];
    const float* lnvb   = (const float*)d_in[4];
    const float* pW1    = (const float*)d_in[5];
    const float* pb1    = (const float*)d_in[6];
    const float* pW2    = (const float*)d_in[7];
    const float* pb2    = (const float*)d_in[8];
    const float* lncw   = (const float*)d_in[9];
    const float* lncb   = (const float*)d_in[10];
    const float* fW1    = (const float*)d_in[11];
    const float* fb1    = (const float*)d_in[12];
    const float* fW2    = (const float*)d_in[13];
    const float* fb2    = (const float*)d_in[14];
    const float* fW3    = (const float*)d_in[15];
    const float* fb3    = (const float*)d_in[16];

    int* counts = (int*)d_ws;

    count_kernel<<<1, 1024, 0, stream>>>(ids, counts);
    token_mlp_scale_kernel<<<NBLK_, 512, 0, stream>>>(
        ids, counts, embW, lnvw, lnvb, pW1, pb1, pW2, pb2,
        lncw, lncb, fW1, fb1, fW2, fb2, fW3, fb3,
        (const vfloat4*)scores, (vfloat4*)d_out);
}